// Round 4
// baseline (1477.846 us; speedup 1.0000x reference)
//
#include <hip/hip_runtime.h>

// ---------------------------------------------------------------------------
// GGNN on MI355X (gfx950). Runtime dtype probe (round-3 evidence: floats are
// fp32 — NaN with bf16 reads, finite with probe): flags[0]=1 -> fp32 floats
// AND fp32 output; flags[1]=1 -> int64 edge_index. All input/output kernels
// branch wave-uniformly on flags; intermediates canonical (bf16 h, fp32 agg).
//
// Math restructure (linearity):
//   segment_sum((h@Wc)[src]) == segment_sum(h[src]) @ Wc
//   (aggH@Wc)@W_ih^T == aggH @ (Wc@W_ih^T) =: aggH @ Wcomb
// -> scatter raw h; fold Wc into GRU input weights (built once per launch).
// Pipeline:
//   detect -> weight prep (B-frag order) -> h = x@W_in
//   4x: memset aggH; aggH[dst]+=h[src] (fp32 atomics); h = GRU(aggH,h) in place
//   out = log_softmax(h @ W_out)   (fp32 or bf16 store per flags[0])
// ---------------------------------------------------------------------------

#define DEVI __device__ __forceinline__

typedef __attribute__((ext_vector_type(8))) short short8;
typedef __attribute__((ext_vector_type(4))) float f32x4;

constexpr int N_NODES   = 100000;
constexpr int F_IN      = 256;
constexpr int H_DIM     = 64;
constexpr int C_OUT     = 40;
constexpr int ROW_TILES = N_NODES / 16;   // 6250 exactly

DEVI float bf2f(unsigned short u) {
    unsigned v = ((unsigned)u) << 16;
    float f; __builtin_memcpy(&f, &v, 4); return f;
}
DEVI unsigned short f2bf(float f) {
    unsigned u; __builtin_memcpy(&u, &f, 4);
    unsigned r = u + 0x7FFFu + ((u >> 16) & 1u);   // round-to-nearest-even
    return (unsigned short)(r >> 16);
}
// idx-th element of a float tensor delivered as bf16 (f32flag=0) or fp32 (=1)
DEVI float in_elem(const void* p, size_t idx, int f32flag) {
    return f32flag ? ((const float*)p)[idx]
                   : bf2f(((const unsigned short*)p)[idx]);
}
// 8 consecutive fp32 -> bf16 A-fragment
DEVI short8 f32row_to_frag(const float* __restrict__ p) {
    const f32x4* q = (const f32x4*)p;
    f32x4 lo = q[0], hi = q[1];
    short8 a;
    a[0] = (short)f2bf(lo[0]); a[1] = (short)f2bf(lo[1]);
    a[2] = (short)f2bf(lo[2]); a[3] = (short)f2bf(lo[3]);
    a[4] = (short)f2bf(hi[0]); a[5] = (short)f2bf(hi[1]);
    a[6] = (short)f2bf(hi[2]); a[7] = (short)f2bf(hi[3]);
    return a;
}

// ---------------------------------------------------------------------------
// Runtime input-encoding probe.
// flags[0]=1 if floats are fp32 (bf16 N(0,1) -> ~256/256 sane exponent fields;
// fp32 viewed as ushorts -> ~150/256). flags[1]=1 if edge_index is int64
// (odd 32-bit words all zero since values < 2^31).
// ---------------------------------------------------------------------------
__global__ void detect_kernel(const void* x, const int* ei, int* flags) {
    if (threadIdx.x != 0 || blockIdx.x != 0) return;
    const unsigned short* u = (const unsigned short*)x;
    int sane = 0;
    for (int i = 0; i < 256; ++i) {
        int e = (u[i] >> 7) & 0xFF;
        if (e >= 100 && e <= 145) sane++;
    }
    flags[0] = (sane < 230) ? 1 : 0;
    int zeros = 0;
    for (int i = 0; i < 64; ++i)
        if (ei[2 * i + 1] == 0) zeros++;
    flags[1] = (zeros >= 63) ? 1 : 0;
}

// ---------------------------------------------------------------------------
// Shuffle row-major [K x ncols_real] weights into MFMA B-fragment order:
// dst[((kb*npad+jt)*64+lane)*8+i] = W[kb*32+(lane>>4)*8+i][jt*16+(lane&15)]
// ---------------------------------------------------------------------------
__global__ void prep_bfrag(const void* __restrict__ src,
                           unsigned short* __restrict__ dst,
                           int K, int npad_tiles, int ncols_real,
                           const int* __restrict__ flags) {
    int f32 = flags[0];
    int t = blockIdx.x * blockDim.x + threadIdx.x;
    int total = (K / 32) * npad_tiles * 512;
    if (t >= total) return;
    int i    = t & 7;
    int lane = (t >> 3) & 63;
    int jt   = (t >> 9) % npad_tiles;
    int kb   = t / (512 * npad_tiles);
    int k    = kb * 32 + ((lane >> 4) << 3) + i;
    int col  = jt * 16 + (lane & 15);
    unsigned short v = 0;
    if (col < ncols_real) v = f2bf(in_elem(src, (size_t)k * ncols_real + col, f32));
    dst[t] = v;
}

// ---------------------------------------------------------------------------
// Wcomb[l][k][g] = sum_j Wc[l][k][j] * w_ih[g][j], in B-frag order:
// dst[l*12288 + ((kb*12+jt)*64+lane)*8+i], k=kb*32+quad*8+i, g=jt*16+l15
// grid (24,4) x 64
// ---------------------------------------------------------------------------
__global__ __launch_bounds__(64) void wcomb_kernel(
        const void* __restrict__ conv_w,   // [4,64,64]
        const void* __restrict__ w_ih,     // [192,64]
        unsigned short* __restrict__ wcomb,
        const int* __restrict__ flags) {
    int f32 = flags[0];
    int lane = threadIdx.x;
    int c = blockIdx.x;             // kb*12 + jt
    int l = blockIdx.y;             // layer
    int kb = c / 12, jt = c % 12;
    int quad = lane >> 4, l15 = lane & 15;
    int g = jt * 16 + l15;
    unsigned short* dst = wcomb + (size_t)l * 12288 + ((size_t)c * 64 + lane) * 8;
#pragma unroll
    for (int i = 0; i < 8; ++i) {
        int k = kb * 32 + quad * 8 + i;
        float acc = 0.0f;
        for (int j = 0; j < 64; ++j)
            acc += in_elem(conv_w, (size_t)l * 4096 + k * 64 + j, f32) *
                   in_elem(w_ih, (size_t)g * 64 + j, f32);
        dst[i] = f2bf(acc);
    }
}

// ---------------------------------------------------------------------------
// Canonical bf16 copies of w_hh [192*64] and biases (b_ih|b_hh) [384]
// ---------------------------------------------------------------------------
__global__ void prep_gruw(const void* __restrict__ w_hh,
                          const void* __restrict__ b_ih,
                          const void* __restrict__ b_hh,
                          unsigned short* __restrict__ whh_c,
                          unsigned short* __restrict__ bias_c,
                          const int* __restrict__ flags) {
    int f32 = flags[0];
    int t = blockIdx.x * blockDim.x + threadIdx.x;
    if (t < 12288)            whh_c[t]          = f2bf(in_elem(w_hh, t, f32));
    else if (t < 12288 + 192) bias_c[t - 12288] = f2bf(in_elem(b_ih, t - 12288, f32));
    else if (t < 12288 + 384) bias_c[t - 12288] = f2bf(in_elem(b_hh, t - 12480, f32));
}

// ---------------------------------------------------------------------------
// h[N,64](bf16) = x[N,256] @ W_in[256,64]
// ---------------------------------------------------------------------------
template <int XF32>
DEVI void proj_in_body(const void* __restrict__ xr,
                       const unsigned short* __restrict__ wfrag,
                       unsigned short* __restrict__ h) {
    int wid = blockIdx.x * 4 + (threadIdx.x >> 6);
    if (wid >= ROW_TILES) return;
    int lane = threadIdx.x & 63;
    int l15 = lane & 15, quad = lane >> 4;
    int row0 = wid * 16;
    int arow = row0 + l15;

    f32x4 acc[4];
#pragma unroll
    for (int jt = 0; jt < 4; ++jt) acc[jt] = (f32x4)(0.0f);

#pragma unroll
    for (int kb = 0; kb < 8; ++kb) {
        short8 a;
        if (XF32)
            a = f32row_to_frag((const float*)xr + (size_t)arow * F_IN + kb * 32 + quad * 8);
        else
            a = *(const short8*)((const unsigned short*)xr + (size_t)arow * F_IN + kb * 32 + quad * 8);
#pragma unroll
        for (int jt = 0; jt < 4; ++jt) {
            short8 b = *(const short8*)(wfrag + (size_t)((kb * 4 + jt) * 64 + lane) * 8);
            acc[jt] = __builtin_amdgcn_mfma_f32_16x16x32_bf16(a, b, acc[jt], 0, 0, 0);
        }
    }
#pragma unroll
    for (int jt = 0; jt < 4; ++jt)
#pragma unroll
        for (int r = 0; r < 4; ++r)
            h[(size_t)(row0 + quad * 4 + r) * H_DIM + jt * 16 + l15] = f2bf(acc[jt][r]);
}

__global__ __launch_bounds__(256) void proj_in_kernel(
        const void* __restrict__ x,
        const unsigned short* __restrict__ wfrag,
        unsigned short* __restrict__ h,
        const int* __restrict__ flags) {
    if (flags[0]) proj_in_body<1>(x, wfrag, h);
    else          proj_in_body<0>(x, wfrag, h);
}

// ---------------------------------------------------------------------------
// aggH[dst[e]][j] += h[src[e]][j] — one wave per edge, lane = channel.
// int64 edge_index: src[e]=ei32[2e], dst[e]=ei32[2E+2e] (high words zero).
// Indices clamped: wrong dtype guess yields finite-wrong, never corruption.
// ---------------------------------------------------------------------------
__global__ __launch_bounds__(256) void scatter_kernel(
        const unsigned short* __restrict__ h,
        const int* __restrict__ ei,
        float* __restrict__ agg,
        int nedges,
        const int* __restrict__ flags) {
    int e = blockIdx.x * 4 + (threadIdx.x >> 6);
    if (e >= nedges) return;
    int j = threadIdx.x & 63;
    int s, d;
    if (flags[1]) { s = ei[2 * (size_t)e];  d = ei[2 * ((size_t)nedges + e)]; }
    else          { s = ei[(size_t)e];      d = ei[(size_t)nedges + e]; }
    if ((unsigned)s >= (unsigned)N_NODES || (unsigned)d >= (unsigned)N_NODES) return;
    float v = bf2f(h[(size_t)s * H_DIM + j]);
    atomicAdd(agg + (size_t)d * H_DIM + j, v);
}

// ---------------------------------------------------------------------------
// Fused GRUCell, h in place:
//   gi = aggH@Wcomb + b_ih ; gh = h@w_hh^T + b_hh
//   r=sig(i_r+h_r); z=sig(i_z+h_z); n=tanh(i_n + r*h_n); h=(1-z)n + z h
// ---------------------------------------------------------------------------
__global__ __launch_bounds__(256) void gru_kernel(
        const float* __restrict__ agg,
        unsigned short* __restrict__ h,
        const unsigned short* __restrict__ wcomb_l,   // B-frag [2*12*64*8]
        const unsigned short* __restrict__ whh_c,     // [192,64] row-major bf16
        const unsigned short* __restrict__ bias_c) {  // b_ih[0:192] | b_hh[192:384]
    int wid = blockIdx.x * 4 + (threadIdx.x >> 6);
    if (wid >= ROW_TILES) return;
    int lane = threadIdx.x & 63;
    int l15 = lane & 15, quad = lane >> 4;
    int row0 = wid * 16;
    int arow = row0 + l15;

    f32x4 gi[12], gh[12];
#pragma unroll
    for (int jt = 0; jt < 12; ++jt) { gi[jt] = (f32x4)(0.0f); gh[jt] = (f32x4)(0.0f); }

#pragma unroll
    for (int kb = 0; kb < 2; ++kb) {
        short8 aa = f32row_to_frag(agg + (size_t)arow * H_DIM + kb * 32 + quad * 8);
        short8 ah = *(const short8*)(h + (size_t)arow * H_DIM + kb * 32 + quad * 8);
#pragma unroll
        for (int jt = 0; jt < 12; ++jt) {
            short8 bi = *(const short8*)(wcomb_l + (size_t)((kb * 12 + jt) * 64 + lane) * 8);
            gi[jt] = __builtin_amdgcn_mfma_f32_16x16x32_bf16(aa, bi, gi[jt], 0, 0, 0);
            short8 bh = *(const short8*)(whh_c + (size_t)(jt * 16 + l15) * H_DIM + kb * 32 + quad * 8);
            gh[jt] = __builtin_amdgcn_mfma_f32_16x16x32_bf16(ah, bh, gh[jt], 0, 0, 0);
        }
    }

#pragma unroll
    for (int jc = 0; jc < 4; ++jc) {
        int j = jc * 16 + l15;
        float bir = bf2f(bias_c[j]),       bhr = bf2f(bias_c[192 + j]);
        float biz = bf2f(bias_c[64 + j]),  bhz = bf2f(bias_c[256 + j]);
        float bin = bf2f(bias_c[128 + j]), bhn = bf2f(bias_c[320 + j]);
#pragma unroll
        for (int r = 0; r < 4; ++r) {
            int row = row0 + quad * 4 + r;
            float xr = (gi[jc][r] + bir) + (gh[jc][r] + bhr);
            float xz = (gi[4 + jc][r] + biz) + (gh[4 + jc][r] + bhz);
            float in_ = gi[8 + jc][r] + bin;
            float hn_ = gh[8 + jc][r] + bhn;
            xr = fminf(fmaxf(xr, -30.0f), 30.0f);
            xz = fminf(fmaxf(xz, -30.0f), 30.0f);
            float rg = 1.0f / (1.0f + __expf(-xr));
            float zg = 1.0f / (1.0f + __expf(-xz));
            float na = in_ + rg * hn_;
            float ey = __expf(-2.0f * fabsf(na));          // (0,1] — safe tanh
            float th = (1.0f - ey) / (1.0f + ey);
            float nt = (na < 0.0f) ? -th : th;
            float ho = bf2f(h[(size_t)row * H_DIM + j]);
            h[(size_t)row * H_DIM + j] = f2bf((1.0f - zg) * nt + zg * ho);
        }
    }
}

// ---------------------------------------------------------------------------
// out[N,40] = log_softmax(h @ W_out[64,40]) — W_out padded to 48 cols.
// Store dtype follows flags[0]: fp32 when inputs are fp32, else bf16.
// ---------------------------------------------------------------------------
__global__ __launch_bounds__(256) void projout_kernel(
        const unsigned short* __restrict__ h,
        const unsigned short* __restrict__ wofrag,
        void* __restrict__ out,
        const int* __restrict__ flags) {
    int f32out = flags[0];
    int wid = blockIdx.x * 4 + (threadIdx.x >> 6);
    if (wid >= ROW_TILES) return;
    int lane = threadIdx.x & 63;
    int l15 = lane & 15, quad = lane >> 4;
    int row0 = wid * 16;
    int arow = row0 + l15;

    f32x4 acc[3];
#pragma unroll
    for (int jt = 0; jt < 3; ++jt) acc[jt] = (f32x4)(0.0f);

#pragma unroll
    for (int kb = 0; kb < 2; ++kb) {
        short8 a = *(const short8*)(h + (size_t)arow * H_DIM + kb * 32 + quad * 8);
#pragma unroll
        for (int jt = 0; jt < 3; ++jt) {
            short8 b = *(const short8*)(wofrag + (size_t)((kb * 3 + jt) * 64 + lane) * 8);
            acc[jt] = __builtin_amdgcn_mfma_f32_16x16x32_bf16(a, b, acc[jt], 0, 0, 0);
        }
    }

    float* of = (float*)out;
    unsigned short* ob = (unsigned short*)out;
    bool valid2 = (l15 < 8);   // tile 2 covers cols 32..47; only 32..39 real
#pragma unroll
    for (int r = 0; r < 4; ++r) {
        int row = row0 + quad * 4 + r;
        float v0 = acc[0][r], v1 = acc[1][r], v2 = acc[2][r];
        float mx = fmaxf(v0, v1);
        if (valid2) mx = fmaxf(mx, v2);
#pragma unroll
        for (int d = 1; d < 16; d <<= 1) mx = fmaxf(mx, __shfl_xor(mx, d));
        float s = __expf(v0 - mx) + __expf(v1 - mx) + (valid2 ? __expf(v2 - mx) : 0.0f);
#pragma unroll
        for (int d = 1; d < 16; d <<= 1) s += __shfl_xor(s, d);
        float lg = mx + __logf(s);
        size_t o0 = (size_t)row * C_OUT + l15;
        if (f32out) {
            of[o0]      = v0 - lg;
            of[o0 + 16] = v1 - lg;
            if (valid2) of[o0 + 32] = v2 - lg;
        } else {
            ob[o0]      = f2bf(v0 - lg);
            ob[o0 + 16] = f2bf(v1 - lg);
            if (valid2) ob[o0 + 32] = f2bf(v2 - lg);
        }
    }
}

// ---------------------------------------------------------------------------
extern "C" void kernel_launch(void* const* d_in, const int* in_sizes, int n_in,
                              void* d_out, int out_size, void* d_ws, size_t ws_size,
                              hipStream_t stream) {
    const void* x      = d_in[0];
    const int*  ei     = (const int*)d_in[1];
    const void* w_in   = d_in[2];
    const void* w_out  = d_in[3];
    const void* conv_w = d_in[4];
    const void* w_ih   = d_in[5];
    const void* w_hh   = d_in[6];
    const void* b_ih   = d_in[7];
    const void* b_hh   = d_in[8];

    const int E = in_sizes[1] / 2;   // element count of [2,E] edge_index

    // workspace carve-up (256B aligned). Total ~38.6 MB.
    char* ws = (char*)d_ws;
    size_t off = 0;
    auto carve = [&](size_t bytes) {
        void* p = ws + off;
        off += (bytes + 255) & ~(size_t)255;
        return p;
    };
    int*            flags   = (int*)carve(256);
    float*          aggH    = (float*)carve((size_t)N_NODES * H_DIM * 4);          // 25.6 MB
    unsigned short* hbuf    = (unsigned short*)carve((size_t)N_NODES * H_DIM * 2); // 12.8 MB
    unsigned short* winfrag = (unsigned short*)carve((size_t)8 * 4 * 512 * 2);
    unsigned short* wcomb   = (unsigned short*)carve((size_t)4 * 12288 * 2);
    unsigned short* wofrag  = (unsigned short*)carve((size_t)3072 * 2);
    unsigned short* whh_c   = (unsigned short*)carve((size_t)12288 * 2);
    unsigned short* bias_c  = (unsigned short*)carve((size_t)384 * 2);

    // ---- input-encoding probe ----
    detect_kernel<<<1, 64, 0, stream>>>(x, ei, flags);

    // ---- weight prep ----
    prep_bfrag<<<64, 256, 0, stream>>>(w_in, winfrag, 256, 4, 64, flags);
    prep_bfrag<<<12, 256, 0, stream>>>(w_out, wofrag, 64, 3, 40, flags);
    wcomb_kernel<<<dim3(24, 4), 64, 0, stream>>>(conv_w, w_ih, wcomb, flags);
    prep_gruw<<<50, 256, 0, stream>>>(w_hh, b_ih, b_hh, whh_c, bias_c, flags);

    const int gblocks = (ROW_TILES + 3) / 4;  // 1563

    // ---- input projection ----
    proj_in_kernel<<<gblocks, 256, 0, stream>>>(x, winfrag, hbuf, flags);

    // ---- GGNN layers ----
    for (int l = 0; l < 4; ++l) {
        hipMemsetAsync(aggH, 0, (size_t)N_NODES * H_DIM * 4, stream);
        scatter_kernel<<<(E + 3) / 4, 256, 0, stream>>>(hbuf, ei, aggH, E, flags);
        gru_kernel<<<gblocks, 256, 0, stream>>>(aggH, hbuf, wcomb + (size_t)l * 12288,
                                                whh_c, bias_c);
    }

    // ---- output projection + log_softmax ----
    projout_kernel<<<gblocks, 256, 0, stream>>>(hbuf, wofrag, d_out, flags);
}

// Round 5
// 828.356 us; speedup vs baseline: 1.7841x; 1.7841x over previous
//
#include <hip/hip_runtime.h>

// ---------------------------------------------------------------------------
// GGNN on MI355X (gfx950). Runtime dtype probe (round-3/4 evidence: floats
// are fp32, output fp32): flags[0]=1 -> fp32 floats + fp32 out; flags[1]=1 ->
// int64 edge_index. Intermediates canonical: h bf16, agg bf16 (fp32 register
// accumulate).
//
// Round-5 change: scatter atomics (4x265us, 72% of total, TCC-RMW-bound at
// 290G atomics/s) replaced by per-launch CSR build + per-node gather:
//   hist -> block scan -> top scan -> fixup -> fill  (int ops, ~40us once)
//   per layer: gather_agg (one wave/node, lane=channel, register accumulate)
// Math restructure (linearity), as before:
//   segment_sum((h@Wc)[src]) == segment_sum(h[src]) @ Wc
//   (aggH@Wc)@W_ih^T == aggH @ (Wc@W_ih^T) =: aggH @ Wcomb
// ---------------------------------------------------------------------------

#define DEVI __device__ __forceinline__

typedef __attribute__((ext_vector_type(8))) short short8;
typedef __attribute__((ext_vector_type(4))) float f32x4;

constexpr int N_NODES   = 100000;
constexpr int F_IN      = 256;
constexpr int H_DIM     = 64;
constexpr int C_OUT     = 40;
constexpr int ROW_TILES = N_NODES / 16;          // 6250
constexpr int NBLK      = (N_NODES + 1023) / 1024;  // 98

DEVI float bf2f(unsigned short u) {
    unsigned v = ((unsigned)u) << 16;
    float f; __builtin_memcpy(&f, &v, 4); return f;
}
DEVI unsigned short f2bf(float f) {
    unsigned u; __builtin_memcpy(&u, &f, 4);
    unsigned r = u + 0x7FFFu + ((u >> 16) & 1u);   // round-to-nearest-even
    return (unsigned short)(r >> 16);
}
DEVI float in_elem(const void* p, size_t idx, int f32flag) {
    return f32flag ? ((const float*)p)[idx]
                   : bf2f(((const unsigned short*)p)[idx]);
}
DEVI short8 f32row_to_frag(const float* __restrict__ p) {
    const f32x4* q = (const f32x4*)p;
    f32x4 lo = q[0], hi = q[1];
    short8 a;
    a[0] = (short)f2bf(lo[0]); a[1] = (short)f2bf(lo[1]);
    a[2] = (short)f2bf(lo[2]); a[3] = (short)f2bf(lo[3]);
    a[4] = (short)f2bf(hi[0]); a[5] = (short)f2bf(hi[1]);
    a[6] = (short)f2bf(hi[2]); a[7] = (short)f2bf(hi[3]);
    return a;
}
// edge accessors (flags[1]: int64 -> stride-2 int32 words, high word zero)
DEVI int edge_src(const int* ei, int E, int e, int i64) {
    return i64 ? ei[2 * (size_t)e] : ei[(size_t)e];
}
DEVI int edge_dst(const int* ei, int E, int e, int i64) {
    return i64 ? ei[2 * ((size_t)E + e)] : ei[(size_t)E + e];
}

// ---------------------------------------------------------------------------
// Runtime input-encoding probe (validated round 4).
// ---------------------------------------------------------------------------
__global__ void detect_kernel(const void* x, const int* ei, int* flags) {
    if (threadIdx.x != 0 || blockIdx.x != 0) return;
    const unsigned short* u = (const unsigned short*)x;
    int sane = 0;
    for (int i = 0; i < 256; ++i) {
        int e = (u[i] >> 7) & 0xFF;
        if (e >= 100 && e <= 145) sane++;
    }
    flags[0] = (sane < 230) ? 1 : 0;
    int zeros = 0;
    for (int i = 0; i < 64; ++i)
        if (ei[2 * i + 1] == 0) zeros++;
    flags[1] = (zeros >= 63) ? 1 : 0;
}

// ============================ CSR construction =============================
__global__ void hist_kernel(const int* __restrict__ ei, int* __restrict__ counts,
                            int nedges, const int* __restrict__ flags) {
    int e = blockIdx.x * blockDim.x + threadIdx.x;
    if (e >= nedges) return;
    int d = edge_dst(ei, nedges, e, flags[1]);
    atomicAdd(counts + d, 1);
}

// per-1024-block exclusive scan (Hillis-Steele in LDS) + block totals
__global__ __launch_bounds__(1024) void scan_blocks(
        const int* __restrict__ counts, int* __restrict__ rowptr,
        int* __restrict__ blocksum) {
    __shared__ int lds[1024];
    int t = threadIdx.x, b = blockIdx.x;
    int idx = b * 1024 + t;
    int v = (idx < N_NODES) ? counts[idx] : 0;
    lds[t] = v;
    __syncthreads();
    for (int ofs = 1; ofs < 1024; ofs <<= 1) {
        int add = (t >= ofs) ? lds[t - ofs] : 0;
        __syncthreads();
        lds[t] += add;
        __syncthreads();
    }
    int incl = lds[t];
    if (idx < N_NODES) rowptr[idx] = incl - v;      // exclusive within block
    if (t == 1023) blocksum[b] = incl;
}

// serial exclusive scan of NBLK block sums (tiny)
__global__ __launch_bounds__(128) void scan_top(
        const int* __restrict__ blocksum, int* __restrict__ blockoff) {
    __shared__ int lds[NBLK];
    int t = threadIdx.x;
    if (t < NBLK) lds[t] = blocksum[t];
    __syncthreads();
    if (t == 0) {
        int run = 0;
        for (int i = 0; i < NBLK; ++i) { int v = lds[i]; lds[i] = run; run += v; }
    }
    __syncthreads();
    if (t < NBLK) blockoff[t] = lds[t];
}

// add block offsets; also init fill cursor
__global__ __launch_bounds__(1024) void fixup_kernel(
        int* __restrict__ rowptr, const int* __restrict__ blockoff,
        int* __restrict__ cursor) {
    int idx = blockIdx.x * 1024 + threadIdx.x;
    if (idx >= N_NODES) return;
    int r = rowptr[idx] + blockoff[blockIdx.x];
    rowptr[idx] = r;
    cursor[idx] = r;
}

__global__ void fill_kernel(const int* __restrict__ ei, int* __restrict__ cursor,
                            int* __restrict__ esrc, int nedges,
                            const int* __restrict__ flags) {
    int e = blockIdx.x * blockDim.x + threadIdx.x;
    if (e >= nedges) return;
    int i64 = flags[1];
    int d = edge_dst(ei, nedges, e, i64);
    int s = edge_src(ei, nedges, e, i64);
    int slot = atomicAdd(cursor + d, 1);
    esrc[slot] = s;
}

// ============================ weight prep ==================================
// row-major [K x ncols_real] -> MFMA B-frag order
__global__ void prep_bfrag(const void* __restrict__ src,
                           unsigned short* __restrict__ dst,
                           int K, int npad_tiles, int ncols_real,
                           const int* __restrict__ flags) {
    int f32 = flags[0];
    int t = blockIdx.x * blockDim.x + threadIdx.x;
    int total = (K / 32) * npad_tiles * 512;
    if (t >= total) return;
    int i    = t & 7;
    int lane = (t >> 3) & 63;
    int jt   = (t >> 9) % npad_tiles;
    int kb   = t / (512 * npad_tiles);
    int k    = kb * 32 + ((lane >> 4) << 3) + i;
    int col  = jt * 16 + (lane & 15);
    unsigned short v = 0;
    if (col < ncols_real) v = f2bf(in_elem(src, (size_t)k * ncols_real + col, f32));
    dst[t] = v;
}

// Wcomb[l][k][g] = sum_j Wc[l][k][j]*w_ih[g][j], B-frag order
__global__ __launch_bounds__(64) void wcomb_kernel(
        const void* __restrict__ conv_w, const void* __restrict__ w_ih,
        unsigned short* __restrict__ wcomb, const int* __restrict__ flags) {
    int f32 = flags[0];
    int lane = threadIdx.x;
    int c = blockIdx.x;             // kb*12 + jt
    int l = blockIdx.y;
    int kb = c / 12, jt = c % 12;
    int quad = lane >> 4, l15 = lane & 15;
    int g = jt * 16 + l15;
    unsigned short* dst = wcomb + (size_t)l * 12288 + ((size_t)c * 64 + lane) * 8;
#pragma unroll
    for (int i = 0; i < 8; ++i) {
        int k = kb * 32 + quad * 8 + i;
        float acc = 0.0f;
        for (int j = 0; j < 64; ++j)
            acc += in_elem(conv_w, (size_t)l * 4096 + k * 64 + j, f32) *
                   in_elem(w_ih, (size_t)g * 64 + j, f32);
        dst[i] = f2bf(acc);
    }
}

__global__ void prep_gruw(const void* __restrict__ w_hh,
                          const void* __restrict__ b_ih,
                          const void* __restrict__ b_hh,
                          unsigned short* __restrict__ whh_c,
                          unsigned short* __restrict__ bias_c,
                          const int* __restrict__ flags) {
    int f32 = flags[0];
    int t = blockIdx.x * blockDim.x + threadIdx.x;
    if (t < 12288)            whh_c[t]          = f2bf(in_elem(w_hh, t, f32));
    else if (t < 12288 + 192) bias_c[t - 12288] = f2bf(in_elem(b_ih, t - 12288, f32));
    else if (t < 12288 + 384) bias_c[t - 12288] = f2bf(in_elem(b_hh, t - 12480, f32));
}

// ============================ main pipeline ================================
// h[N,64](bf16) = x[N,256] @ W_in[256,64]
template <int XF32>
DEVI void proj_in_body(const void* __restrict__ xr,
                       const unsigned short* __restrict__ wfrag,
                       unsigned short* __restrict__ h) {
    int wid = blockIdx.x * 4 + (threadIdx.x >> 6);
    if (wid >= ROW_TILES) return;
    int lane = threadIdx.x & 63;
    int l15 = lane & 15, quad = lane >> 4;
    int row0 = wid * 16;
    int arow = row0 + l15;

    f32x4 acc[4];
#pragma unroll
    for (int jt = 0; jt < 4; ++jt) acc[jt] = (f32x4)(0.0f);

#pragma unroll
    for (int kb = 0; kb < 8; ++kb) {
        short8 a;
        if (XF32)
            a = f32row_to_frag((const float*)xr + (size_t)arow * F_IN + kb * 32 + quad * 8);
        else
            a = *(const short8*)((const unsigned short*)xr + (size_t)arow * F_IN + kb * 32 + quad * 8);
#pragma unroll
        for (int jt = 0; jt < 4; ++jt) {
            short8 b = *(const short8*)(wfrag + (size_t)((kb * 4 + jt) * 64 + lane) * 8);
            acc[jt] = __builtin_amdgcn_mfma_f32_16x16x32_bf16(a, b, acc[jt], 0, 0, 0);
        }
    }
#pragma unroll
    for (int jt = 0; jt < 4; ++jt)
#pragma unroll
        for (int r = 0; r < 4; ++r)
            h[(size_t)(row0 + quad * 4 + r) * H_DIM + jt * 16 + l15] = f2bf(acc[jt][r]);
}

__global__ __launch_bounds__(256) void proj_in_kernel(
        const void* __restrict__ x,
        const unsigned short* __restrict__ wfrag,
        unsigned short* __restrict__ h,
        const int* __restrict__ flags) {
    if (flags[0]) proj_in_body<1>(x, wfrag, h);
    else          proj_in_body<0>(x, wfrag, h);
}

// aggB[n][j] = sum_{e: dst=n} h[src(e)][j] — one wave/node, lane=channel,
// fp32 register accumulate, bf16 store. No atomics.
__global__ __launch_bounds__(256) void gather_agg(
        const unsigned short* __restrict__ h,
        const int* __restrict__ rowptr,
        const int* __restrict__ counts,
        const int* __restrict__ esrc,
        unsigned short* __restrict__ aggB) {
    int n = blockIdx.x * 4 + (threadIdx.x >> 6);
    if (n >= N_NODES) return;
    int j = threadIdx.x & 63;
    int start = rowptr[n];
    int deg   = counts[n];
    float acc = 0.0f;
    if (deg > 0) {
        int s = esrc[start];
        for (int i = 1; i < deg; ++i) {
            int s_next = esrc[start + i];          // pipelined index load
            acc += bf2f(h[(size_t)s * H_DIM + j]);
            s = s_next;
        }
        acc += bf2f(h[(size_t)s * H_DIM + j]);
    }
    aggB[(size_t)n * H_DIM + j] = f2bf(acc);
}

// Fused GRUCell, h in place (agg now bf16)
__global__ __launch_bounds__(256) void gru_kernel(
        const unsigned short* __restrict__ aggB,
        unsigned short* __restrict__ h,
        const unsigned short* __restrict__ wcomb_l,
        const unsigned short* __restrict__ whh_c,
        const unsigned short* __restrict__ bias_c) {
    int wid = blockIdx.x * 4 + (threadIdx.x >> 6);
    if (wid >= ROW_TILES) return;
    int lane = threadIdx.x & 63;
    int l15 = lane & 15, quad = lane >> 4;
    int row0 = wid * 16;
    int arow = row0 + l15;

    f32x4 gi[12], gh[12];
#pragma unroll
    for (int jt = 0; jt < 12; ++jt) { gi[jt] = (f32x4)(0.0f); gh[jt] = (f32x4)(0.0f); }

#pragma unroll
    for (int kb = 0; kb < 2; ++kb) {
        short8 aa = *(const short8*)(aggB + (size_t)arow * H_DIM + kb * 32 + quad * 8);
        short8 ah = *(const short8*)(h + (size_t)arow * H_DIM + kb * 32 + quad * 8);
#pragma unroll
        for (int jt = 0; jt < 12; ++jt) {
            short8 bi = *(const short8*)(wcomb_l + (size_t)((kb * 12 + jt) * 64 + lane) * 8);
            gi[jt] = __builtin_amdgcn_mfma_f32_16x16x32_bf16(aa, bi, gi[jt], 0, 0, 0);
            short8 bh = *(const short8*)(whh_c + (size_t)(jt * 16 + l15) * H_DIM + kb * 32 + quad * 8);
            gh[jt] = __builtin_amdgcn_mfma_f32_16x16x32_bf16(ah, bh, gh[jt], 0, 0, 0);
        }
    }

#pragma unroll
    for (int jc = 0; jc < 4; ++jc) {
        int j = jc * 16 + l15;
        float bir = bf2f(bias_c[j]),       bhr = bf2f(bias_c[192 + j]);
        float biz = bf2f(bias_c[64 + j]),  bhz = bf2f(bias_c[256 + j]);
        float bin = bf2f(bias_c[128 + j]), bhn = bf2f(bias_c[320 + j]);
#pragma unroll
        for (int r = 0; r < 4; ++r) {
            int row = row0 + quad * 4 + r;
            float xr = (gi[jc][r] + bir) + (gh[jc][r] + bhr);
            float xz = (gi[4 + jc][r] + biz) + (gh[4 + jc][r] + bhz);
            float in_ = gi[8 + jc][r] + bin;
            float hn_ = gh[8 + jc][r] + bhn;
            xr = fminf(fmaxf(xr, -30.0f), 30.0f);
            xz = fminf(fmaxf(xz, -30.0f), 30.0f);
            float rg = 1.0f / (1.0f + __expf(-xr));
            float zg = 1.0f / (1.0f + __expf(-xz));
            float na = in_ + rg * hn_;
            float ey = __expf(-2.0f * fabsf(na));          // (0,1] — safe tanh
            float th = (1.0f - ey) / (1.0f + ey);
            float nt = (na < 0.0f) ? -th : th;
            float ho = bf2f(h[(size_t)row * H_DIM + j]);
            h[(size_t)row * H_DIM + j] = f2bf((1.0f - zg) * nt + zg * ho);
        }
    }
}

// out = log_softmax(h @ W_out[64,40]); store fp32/bf16 per flags[0]
__global__ __launch_bounds__(256) void projout_kernel(
        const unsigned short* __restrict__ h,
        const unsigned short* __restrict__ wofrag,
        void* __restrict__ out,
        const int* __restrict__ flags) {
    int f32out = flags[0];
    int wid = blockIdx.x * 4 + (threadIdx.x >> 6);
    if (wid >= ROW_TILES) return;
    int lane = threadIdx.x & 63;
    int l15 = lane & 15, quad = lane >> 4;
    int row0 = wid * 16;
    int arow = row0 + l15;

    f32x4 acc[3];
#pragma unroll
    for (int jt = 0; jt < 3; ++jt) acc[jt] = (f32x4)(0.0f);

#pragma unroll
    for (int kb = 0; kb < 2; ++kb) {
        short8 a = *(const short8*)(h + (size_t)arow * H_DIM + kb * 32 + quad * 8);
#pragma unroll
        for (int jt = 0; jt < 3; ++jt) {
            short8 b = *(const short8*)(wofrag + (size_t)((kb * 3 + jt) * 64 + lane) * 8);
            acc[jt] = __builtin_amdgcn_mfma_f32_16x16x32_bf16(a, b, acc[jt], 0, 0, 0);
        }
    }

    float* of = (float*)out;
    unsigned short* ob = (unsigned short*)out;
    bool valid2 = (l15 < 8);
#pragma unroll
    for (int r = 0; r < 4; ++r) {
        int row = row0 + quad * 4 + r;
        float v0 = acc[0][r], v1 = acc[1][r], v2 = acc[2][r];
        float mx = fmaxf(v0, v1);
        if (valid2) mx = fmaxf(mx, v2);
#pragma unroll
        for (int d = 1; d < 16; d <<= 1) mx = fmaxf(mx, __shfl_xor(mx, d));
        float s = __expf(v0 - mx) + __expf(v1 - mx) + (valid2 ? __expf(v2 - mx) : 0.0f);
#pragma unroll
        for (int d = 1; d < 16; d <<= 1) s += __shfl_xor(s, d);
        float lg = mx + __logf(s);
        size_t o0 = (size_t)row * C_OUT + l15;
        if (f32out) {
            of[o0]      = v0 - lg;
            of[o0 + 16] = v1 - lg;
            if (valid2) of[o0 + 32] = v2 - lg;
        } else {
            ob[o0]      = f2bf(v0 - lg);
            ob[o0 + 16] = f2bf(v1 - lg);
            if (valid2) ob[o0 + 32] = f2bf(v2 - lg);
        }
    }
}

// ---------------------------------------------------------------------------
extern "C" void kernel_launch(void* const* d_in, const int* in_sizes, int n_in,
                              void* d_out, int out_size, void* d_ws, size_t ws_size,
                              hipStream_t stream) {
    const void* x      = d_in[0];
    const int*  ei     = (const int*)d_in[1];
    const void* w_in   = d_in[2];
    const void* w_out  = d_in[3];
    const void* conv_w = d_in[4];
    const void* w_ih   = d_in[5];
    const void* w_hh   = d_in[6];
    const void* b_ih   = d_in[7];
    const void* b_hh   = d_in[8];

    const int E = in_sizes[1] / 2;

    // workspace carve-up (256B aligned). Total ~32 MB.
    char* ws = (char*)d_ws;
    size_t off = 0;
    auto carve = [&](size_t bytes) {
        void* p = ws + off;
        off += (bytes + 255) & ~(size_t)255;
        return p;
    };
    int*            flags    = (int*)carve(256);
    unsigned short* aggB     = (unsigned short*)carve((size_t)N_NODES * H_DIM * 2); // 12.8 MB
    unsigned short* hbuf     = (unsigned short*)carve((size_t)N_NODES * H_DIM * 2); // 12.8 MB
    int*            counts   = (int*)carve((size_t)N_NODES * 4);
    int*            rowptr   = (int*)carve((size_t)N_NODES * 4);
    int*            cursor   = (int*)carve((size_t)N_NODES * 4);
    int*            blocksum = (int*)carve(NBLK * 4);
    int*            blockoff = (int*)carve(NBLK * 4);
    int*            esrc     = (int*)carve((size_t)E * 4);                           // 4.8 MB
    unsigned short* winfrag  = (unsigned short*)carve((size_t)8 * 4 * 512 * 2);
    unsigned short* wcomb    = (unsigned short*)carve((size_t)4 * 12288 * 2);
    unsigned short* wofrag   = (unsigned short*)carve((size_t)3072 * 2);
    unsigned short* whh_c    = (unsigned short*)carve((size_t)12288 * 2);
    unsigned short* bias_c   = (unsigned short*)carve((size_t)384 * 2);

    // ---- probe ----
    detect_kernel<<<1, 64, 0, stream>>>(x, ei, flags);

    // ---- CSR build (once; reused for all 4 layers) ----
    hipMemsetAsync(counts, 0, (size_t)N_NODES * 4, stream);
    const int eblocks = (E + 255) / 256;
    hist_kernel<<<eblocks, 256, 0, stream>>>(ei, counts, E, flags);
    scan_blocks<<<NBLK, 1024, 0, stream>>>(counts, rowptr, blocksum);
    scan_top<<<1, 128, 0, stream>>>(blocksum, blockoff);
    fixup_kernel<<<NBLK, 1024, 0, stream>>>(rowptr, blockoff, cursor);
    fill_kernel<<<eblocks, 256, 0, stream>>>(ei, cursor, esrc, E, flags);

    // ---- weight prep ----
    prep_bfrag<<<64, 256, 0, stream>>>(w_in, winfrag, 256, 4, 64, flags);
    prep_bfrag<<<12, 256, 0, stream>>>(w_out, wofrag, 64, 3, 40, flags);
    wcomb_kernel<<<dim3(24, 4), 64, 0, stream>>>(conv_w, w_ih, wcomb, flags);
    prep_gruw<<<50, 256, 0, stream>>>(w_hh, b_ih, b_hh, whh_c, bias_c, flags);

    const int gblocks = (ROW_TILES + 3) / 4;  // 1563
    const int nblocks = N_NODES / 4;          // 25000 (one wave per node)

    // ---- input projection ----
    proj_in_kernel<<<gblocks, 256, 0, stream>>>(x, winfrag, hbuf, flags);

    // ---- GGNN layers ----
    for (int l = 0; l < 4; ++l) {
        gather_agg<<<nblocks, 256, 0, stream>>>(hbuf, rowptr, counts, esrc, aggB);
        gru_kernel<<<gblocks, 256, 0, stream>>>(aggB, hbuf, wcomb + (size_t)l * 12288,
                                                whh_c, bias_c);
    }

    // ---- output projection + log_softmax ----
    projout_kernel<<<gblocks, 256, 0, stream>>>(hbuf, wofrag, d_out, flags);
}

// Round 6
// 638.444 us; speedup vs baseline: 2.3148x; 1.2975x over previous
//
#include <hip/hip_runtime.h>

// ---------------------------------------------------------------------------
// GGNN on MI355X (gfx950). Runtime dtype probe (validated round 4): flags[0]=1
// -> fp32 float tensors + fp32 out; flags[1]=1 -> int64 edge_index.
// Intermediates canonical: h bf16, agg bf16 (fp32 register accumulate).
//
// Round-6 change: hist+scan+fixup+fill (scattered 4B stores/atomics, 83MB
// write-amplification, ~165-200us) replaced by an atomic-free two-level
// counting sort:
//   bucket_local: per-wg LDS sort of 8192 edges into 782 dst-buckets (128
//                 nodes each); coalesced writes of sorted list + offsets.
//   bucket_csr:   per-bucket gather of wg segments -> node-level LDS sort;
//                 coalesced rowptr/counts/esrc writes (bucket-padded b*2048).
// Math restructure (linearity), as before:
//   segment_sum((h@Wc)[src]) == segment_sum(h[src]) @ Wc
//   (aggH@Wc)@W_ih^T == aggH @ (Wc@W_ih^T) =: aggH @ Wcomb
// ---------------------------------------------------------------------------

#define DEVI __device__ __forceinline__

typedef __attribute__((ext_vector_type(8))) short short8;
typedef __attribute__((ext_vector_type(4))) float f32x4;

constexpr int N_NODES   = 100000;
constexpr int F_IN      = 256;
constexpr int H_DIM     = 64;
constexpr int C_OUT     = 40;
constexpr int ROW_TILES = N_NODES / 16;             // 6250
constexpr int CH        = 8192;                     // edges per bucket_local wg
constexpr int NBUCK     = (N_NODES + 127) / 128;    // 782 buckets of 128 nodes
constexpr int LB_STRIDE = NBUCK + 1;                // +1 sentinel (wg total)
constexpr int BCAP      = 2048;                     // max edges per bucket (mean 1534)

DEVI float bf2f(unsigned short u) {
    unsigned v = ((unsigned)u) << 16;
    float f; __builtin_memcpy(&f, &v, 4); return f;
}
DEVI unsigned short f2bf(float f) {
    unsigned u; __builtin_memcpy(&u, &f, 4);
    unsigned r = u + 0x7FFFu + ((u >> 16) & 1u);   // round-to-nearest-even
    return (unsigned short)(r >> 16);
}
DEVI float in_elem(const void* p, size_t idx, int f32flag) {
    return f32flag ? ((const float*)p)[idx]
                   : bf2f(((const unsigned short*)p)[idx]);
}
DEVI short8 f32row_to_frag(const float* __restrict__ p) {
    const f32x4* q = (const f32x4*)p;
    f32x4 lo = q[0], hi = q[1];
    short8 a;
    a[0] = (short)f2bf(lo[0]); a[1] = (short)f2bf(lo[1]);
    a[2] = (short)f2bf(lo[2]); a[3] = (short)f2bf(lo[3]);
    a[4] = (short)f2bf(hi[0]); a[5] = (short)f2bf(hi[1]);
    a[6] = (short)f2bf(hi[2]); a[7] = (short)f2bf(hi[3]);
    return a;
}

// ---------------------------------------------------------------------------
__global__ void detect_kernel(const void* x, const int* ei, int* flags) {
    if (threadIdx.x != 0 || blockIdx.x != 0) return;
    const unsigned short* u = (const unsigned short*)x;
    int sane = 0;
    for (int i = 0; i < 256; ++i) {
        int e = (u[i] >> 7) & 0xFF;
        if (e >= 100 && e <= 145) sane++;
    }
    flags[0] = (sane < 230) ? 1 : 0;
    int zeros = 0;
    for (int i = 0; i < 64; ++i)
        if (ei[2 * i + 1] == 0) zeros++;
    flags[1] = (zeros >= 63) ? 1 : 0;
}

// ======================= CSR build: two-level sort =========================
// Pass C: each wg locally sorts its CH edges by dst-bucket (dst>>7) in LDS,
// writes the sorted list (coalesced) + per-bucket exclusive offsets.
__global__ __launch_bounds__(256) void bucket_local(
        const int* __restrict__ ei, int E, const int* __restrict__ flags,
        int* __restrict__ wgsorted,     // [nwg*CH]  packed (ldst<<17 | src)
        int* __restrict__ lbase_g) {    // [nwg*LB_STRIDE]
    __shared__ int hist[NBUCK];
    __shared__ int partial[256];
    __shared__ int staging[CH];
    int tid = threadIdx.x, wg = blockIdx.x;
    int i64 = flags[1];
    int base = wg * CH;
    int cnt_wg = min(CH, E - base);

    for (int i = tid; i < NBUCK; i += 256) hist[i] = 0;
    __syncthreads();
    // pass 1: histogram over dst buckets
    for (int k = tid; k < cnt_wg; k += 256) {
        size_t e = (size_t)base + k;
        int d = i64 ? ei[2 * ((size_t)E + e)] : ei[(size_t)E + e];
        atomicAdd(&hist[d >> 7], 1);
    }
    __syncthreads();
    // exclusive scan of hist (4 elems/thread + 256-wide Hillis-Steele)
    int i0 = 4 * tid;
    int e0 = (i0 + 0 < NBUCK) ? hist[i0 + 0] : 0;
    int e1 = (i0 + 1 < NBUCK) ? hist[i0 + 1] : 0;
    int e2 = (i0 + 2 < NBUCK) ? hist[i0 + 2] : 0;
    int e3 = (i0 + 3 < NBUCK) ? hist[i0 + 3] : 0;
    int s0 = e0, s1 = s0 + e1, s2 = s1 + e2, s3 = s2 + e3;
    __syncthreads();
    partial[tid] = s3;
    __syncthreads();
    for (int ofs = 1; ofs < 256; ofs <<= 1) {
        int add = (tid >= ofs) ? partial[tid - ofs] : 0;
        __syncthreads();
        partial[tid] += add;
        __syncthreads();
    }
    int pbase = (tid > 0) ? partial[tid - 1] : 0;
    if (i0 + 0 < NBUCK) hist[i0 + 0] = pbase;
    if (i0 + 1 < NBUCK) hist[i0 + 1] = pbase + s0;
    if (i0 + 2 < NBUCK) hist[i0 + 2] = pbase + s1;
    if (i0 + 3 < NBUCK) hist[i0 + 3] = pbase + s2;
    __syncthreads();
    // export offsets (coalesced) before hist is consumed as cursor
    int* lb = lbase_g + (size_t)wg * LB_STRIDE;
    for (int i = tid; i < NBUCK; i += 256) lb[i] = hist[i];
    if (tid == 0) lb[NBUCK] = cnt_wg;
    __syncthreads();
    // pass 2: rank (hist as cursor) + LDS stage
    for (int k = tid; k < cnt_wg; k += 256) {
        size_t e = (size_t)base + k;
        int s, d;
        if (i64) { s = ei[2 * e]; d = ei[2 * ((size_t)E + e)]; }
        else     { s = ei[e];     d = ei[(size_t)E + e]; }
        int pos = atomicAdd(&hist[d >> 7], 1);
        staging[pos] = ((d & 127) << 17) | s;     // src < 2^17
    }
    __syncthreads();
    // coalesced export
    for (int k = tid; k < cnt_wg; k += 256)
        wgsorted[(size_t)base + k] = staging[k];
}

// Pass D: one wg per bucket. Gather the bucket's segments from all wgs,
// node-level LDS counting sort, write rowptr/counts/esrc (coalesced).
__global__ __launch_bounds__(256) void bucket_csr(
        const int* __restrict__ wgsorted,
        const int* __restrict__ lbase_g,
        int nwg,
        int* __restrict__ rowptr,
        int* __restrict__ counts,
        int* __restrict__ esrc) {       // [NBUCK*BCAP] padded
    __shared__ int segofs[256];
    __shared__ int edata[BCAP];
    __shared__ int sout[BCAP];
    __shared__ int hist2[128];
    __shared__ int cur2[128];
    int tid = threadIdx.x, b = blockIdx.x;

    int lbv = 0, cntv = 0;
    if (tid < nwg) {
        const int* lb = lbase_g + (size_t)tid * LB_STRIDE;
        lbv  = lb[b];
        cntv = lb[b + 1] - lbv;      // sentinel handles b == NBUCK-1
    }
    segofs[tid] = cntv;
    __syncthreads();
    for (int ofs = 1; ofs < 256; ofs <<= 1) {
        int add = (tid >= ofs) ? segofs[tid - ofs] : 0;
        __syncthreads();
        segofs[tid] += add;
        __syncthreads();
    }
    int tot = segofs[255];
    int myofs = (tid > 0) ? segofs[tid - 1] : 0;
    if (tot > BCAP) tot = BCAP;      // safety clamp (13-sigma margin)
    // gather my wg's segment into LDS
    if (tid < nwg && cntv > 0) {
        const int* srcp = wgsorted + (size_t)tid * CH + lbv;
        for (int i = 0; i < cntv; ++i) {
            int o = myofs + i;
            if (o < BCAP) edata[o] = srcp[i];
        }
    }
    if (tid < 128) hist2[tid] = 0;
    __syncthreads();
    for (int i = tid; i < tot; i += 256) atomicAdd(&hist2[edata[i] >> 17], 1);
    __syncthreads();
    // scan 128 node counters
    if (tid < 128) cur2[tid] = hist2[tid];
    __syncthreads();
    for (int ofs = 1; ofs < 128; ofs <<= 1) {
        int add = 0;
        if (tid < 128 && tid >= ofs) add = cur2[tid - ofs];
        __syncthreads();
        if (tid < 128) cur2[tid] += add;
        __syncthreads();
    }
    int nodeexcl = 0;
    if (tid < 128) nodeexcl = (tid > 0) ? cur2[tid - 1] : 0;
    __syncthreads();
    if (tid < 128) {
        int node = b * 128 + tid;
        if (node < N_NODES) {
            counts[node] = hist2[tid];
            rowptr[node] = b * BCAP + nodeexcl;
        }
        cur2[tid] = nodeexcl;        // becomes cursor
    }
    __syncthreads();
    for (int i = tid; i < tot; i += 256) {
        int p = edata[i];
        int pos = atomicAdd(&cur2[p >> 17], 1);
        sout[pos] = p & 0x1FFFF;
    }
    __syncthreads();
    for (int i = tid; i < tot; i += 256)
        esrc[(size_t)b * BCAP + i] = sout[i];
}

// ============================ weight prep ==================================
__global__ void prep_bfrag(const void* __restrict__ src,
                           unsigned short* __restrict__ dst,
                           int K, int npad_tiles, int ncols_real,
                           const int* __restrict__ flags) {
    int f32 = flags[0];
    int t = blockIdx.x * blockDim.x + threadIdx.x;
    int total = (K / 32) * npad_tiles * 512;
    if (t >= total) return;
    int i    = t & 7;
    int lane = (t >> 3) & 63;
    int jt   = (t >> 9) % npad_tiles;
    int kb   = t / (512 * npad_tiles);
    int k    = kb * 32 + ((lane >> 4) << 3) + i;
    int col  = jt * 16 + (lane & 15);
    unsigned short v = 0;
    if (col < ncols_real) v = f2bf(in_elem(src, (size_t)k * ncols_real + col, f32));
    dst[t] = v;
}

__global__ __launch_bounds__(64) void wcomb_kernel(
        const void* __restrict__ conv_w, const void* __restrict__ w_ih,
        unsigned short* __restrict__ wcomb, const int* __restrict__ flags) {
    int f32 = flags[0];
    int lane = threadIdx.x;
    int c = blockIdx.x;
    int l = blockIdx.y;
    int kb = c / 12, jt = c % 12;
    int quad = lane >> 4, l15 = lane & 15;
    int g = jt * 16 + l15;
    unsigned short* dst = wcomb + (size_t)l * 12288 + ((size_t)c * 64 + lane) * 8;
#pragma unroll
    for (int i = 0; i < 8; ++i) {
        int k = kb * 32 + quad * 8 + i;
        float acc = 0.0f;
        for (int j = 0; j < 64; ++j)
            acc += in_elem(conv_w, (size_t)l * 4096 + k * 64 + j, f32) *
                   in_elem(w_ih, (size_t)g * 64 + j, f32);
        dst[i] = f2bf(acc);
    }
}

__global__ void prep_gruw(const void* __restrict__ w_hh,
                          const void* __restrict__ b_ih,
                          const void* __restrict__ b_hh,
                          unsigned short* __restrict__ whh_c,
                          unsigned short* __restrict__ bias_c,
                          const int* __restrict__ flags) {
    int f32 = flags[0];
    int t = blockIdx.x * blockDim.x + threadIdx.x;
    if (t < 12288)            whh_c[t]          = f2bf(in_elem(w_hh, t, f32));
    else if (t < 12288 + 192) bias_c[t - 12288] = f2bf(in_elem(b_ih, t - 12288, f32));
    else if (t < 12288 + 384) bias_c[t - 12288] = f2bf(in_elem(b_hh, t - 12480, f32));
}

// ============================ main pipeline ================================
template <int XF32>
DEVI void proj_in_body(const void* __restrict__ xr,
                       const unsigned short* __restrict__ wfrag,
                       unsigned short* __restrict__ h) {
    int wid = blockIdx.x * 4 + (threadIdx.x >> 6);
    if (wid >= ROW_TILES) return;
    int lane = threadIdx.x & 63;
    int l15 = lane & 15, quad = lane >> 4;
    int row0 = wid * 16;
    int arow = row0 + l15;

    f32x4 acc[4];
#pragma unroll
    for (int jt = 0; jt < 4; ++jt) acc[jt] = (f32x4)(0.0f);

#pragma unroll
    for (int kb = 0; kb < 8; ++kb) {
        short8 a;
        if (XF32)
            a = f32row_to_frag((const float*)xr + (size_t)arow * F_IN + kb * 32 + quad * 8);
        else
            a = *(const short8*)((const unsigned short*)xr + (size_t)arow * F_IN + kb * 32 + quad * 8);
#pragma unroll
        for (int jt = 0; jt < 4; ++jt) {
            short8 b = *(const short8*)(wfrag + (size_t)((kb * 4 + jt) * 64 + lane) * 8);
            acc[jt] = __builtin_amdgcn_mfma_f32_16x16x32_bf16(a, b, acc[jt], 0, 0, 0);
        }
    }
#pragma unroll
    for (int jt = 0; jt < 4; ++jt)
#pragma unroll
        for (int r = 0; r < 4; ++r)
            h[(size_t)(row0 + quad * 4 + r) * H_DIM + jt * 16 + l15] = f2bf(acc[jt][r]);
}

__global__ __launch_bounds__(256) void proj_in_kernel(
        const void* __restrict__ x,
        const unsigned short* __restrict__ wfrag,
        unsigned short* __restrict__ h,
        const int* __restrict__ flags) {
    if (flags[0]) proj_in_body<1>(x, wfrag, h);
    else          proj_in_body<0>(x, wfrag, h);
}

// aggB[n][j] = sum_{e: dst=n} h[src(e)][j] — one wave/node, lane=channel,
// 4 independent accumulators for load-level parallelism. No atomics.
__global__ __launch_bounds__(256) void gather_agg(
        const unsigned short* __restrict__ h,
        const int* __restrict__ rowptr,
        const int* __restrict__ counts,
        const int* __restrict__ esrc,
        unsigned short* __restrict__ aggB) {
    int n = blockIdx.x * 4 + (threadIdx.x >> 6);
    if (n >= N_NODES) return;
    int j = threadIdx.x & 63;
    int start = rowptr[n];
    int deg   = counts[n];
    float a0 = 0.f, a1 = 0.f, a2 = 0.f, a3 = 0.f;
    int i = 0;
    for (; i + 4 <= deg; i += 4) {
        int s0 = esrc[start + i],     s1 = esrc[start + i + 1];
        int s2 = esrc[start + i + 2], s3 = esrc[start + i + 3];
        a0 += bf2f(h[(size_t)s0 * H_DIM + j]);
        a1 += bf2f(h[(size_t)s1 * H_DIM + j]);
        a2 += bf2f(h[(size_t)s2 * H_DIM + j]);
        a3 += bf2f(h[(size_t)s3 * H_DIM + j]);
    }
    for (; i < deg; ++i)
        a0 += bf2f(h[(size_t)esrc[start + i] * H_DIM + j]);
    aggB[(size_t)n * H_DIM + j] = f2bf((a0 + a1) + (a2 + a3));
}

// Fused GRUCell, h in place
__global__ __launch_bounds__(256) void gru_kernel(
        const unsigned short* __restrict__ aggB,
        unsigned short* __restrict__ h,
        const unsigned short* __restrict__ wcomb_l,
        const unsigned short* __restrict__ whh_c,
        const unsigned short* __restrict__ bias_c) {
    int wid = blockIdx.x * 4 + (threadIdx.x >> 6);
    if (wid >= ROW_TILES) return;
    int lane = threadIdx.x & 63;
    int l15 = lane & 15, quad = lane >> 4;
    int row0 = wid * 16;
    int arow = row0 + l15;

    f32x4 gi[12], gh[12];
#pragma unroll
    for (int jt = 0; jt < 12; ++jt) { gi[jt] = (f32x4)(0.0f); gh[jt] = (f32x4)(0.0f); }

#pragma unroll
    for (int kb = 0; kb < 2; ++kb) {
        short8 aa = *(const short8*)(aggB + (size_t)arow * H_DIM + kb * 32 + quad * 8);
        short8 ah = *(const short8*)(h + (size_t)arow * H_DIM + kb * 32 + quad * 8);
#pragma unroll
        for (int jt = 0; jt < 12; ++jt) {
            short8 bi = *(const short8*)(wcomb_l + (size_t)((kb * 12 + jt) * 64 + lane) * 8);
            gi[jt] = __builtin_amdgcn_mfma_f32_16x16x32_bf16(aa, bi, gi[jt], 0, 0, 0);
            short8 bh = *(const short8*)(whh_c + (size_t)(jt * 16 + l15) * H_DIM + kb * 32 + quad * 8);
            gh[jt] = __builtin_amdgcn_mfma_f32_16x16x32_bf16(ah, bh, gh[jt], 0, 0, 0);
        }
    }

#pragma unroll
    for (int jc = 0; jc < 4; ++jc) {
        int j = jc * 16 + l15;
        float bir = bf2f(bias_c[j]),       bhr = bf2f(bias_c[192 + j]);
        float biz = bf2f(bias_c[64 + j]),  bhz = bf2f(bias_c[256 + j]);
        float bin = bf2f(bias_c[128 + j]), bhn = bf2f(bias_c[320 + j]);
#pragma unroll
        for (int r = 0; r < 4; ++r) {
            int row = row0 + quad * 4 + r;
            float xr = (gi[jc][r] + bir) + (gh[jc][r] + bhr);
            float xz = (gi[4 + jc][r] + biz) + (gh[4 + jc][r] + bhz);
            float in_ = gi[8 + jc][r] + bin;
            float hn_ = gh[8 + jc][r] + bhn;
            xr = fminf(fmaxf(xr, -30.0f), 30.0f);
            xz = fminf(fmaxf(xz, -30.0f), 30.0f);
            float rg = 1.0f / (1.0f + __expf(-xr));
            float zg = 1.0f / (1.0f + __expf(-xz));
            float na = in_ + rg * hn_;
            float ey = __expf(-2.0f * fabsf(na));          // (0,1] — safe tanh
            float th = (1.0f - ey) / (1.0f + ey);
            float nt = (na < 0.0f) ? -th : th;
            float ho = bf2f(h[(size_t)row * H_DIM + j]);
            h[(size_t)row * H_DIM + j] = f2bf((1.0f - zg) * nt + zg * ho);
        }
    }
}

// out = log_softmax(h @ W_out[64,40]); store fp32/bf16 per flags[0]
__global__ __launch_bounds__(256) void projout_kernel(
        const unsigned short* __restrict__ h,
        const unsigned short* __restrict__ wofrag,
        void* __restrict__ out,
        const int* __restrict__ flags) {
    int f32out = flags[0];
    int wid = blockIdx.x * 4 + (threadIdx.x >> 6);
    if (wid >= ROW_TILES) return;
    int lane = threadIdx.x & 63;
    int l15 = lane & 15, quad = lane >> 4;
    int row0 = wid * 16;
    int arow = row0 + l15;

    f32x4 acc[3];
#pragma unroll
    for (int jt = 0; jt < 3; ++jt) acc[jt] = (f32x4)(0.0f);

#pragma unroll
    for (int kb = 0; kb < 2; ++kb) {
        short8 a = *(const short8*)(h + (size_t)arow * H_DIM + kb * 32 + quad * 8);
#pragma unroll
        for (int jt = 0; jt < 3; ++jt) {
            short8 b = *(const short8*)(wofrag + (size_t)((kb * 3 + jt) * 64 + lane) * 8);
            acc[jt] = __builtin_amdgcn_mfma_f32_16x16x32_bf16(a, b, acc[jt], 0, 0, 0);
        }
    }

    float* of = (float*)out;
    unsigned short* ob = (unsigned short*)out;
    bool valid2 = (l15 < 8);
#pragma unroll
    for (int r = 0; r < 4; ++r) {
        int row = row0 + quad * 4 + r;
        float v0 = acc[0][r], v1 = acc[1][r], v2 = acc[2][r];
        float mx = fmaxf(v0, v1);
        if (valid2) mx = fmaxf(mx, v2);
#pragma unroll
        for (int d = 1; d < 16; d <<= 1) mx = fmaxf(mx, __shfl_xor(mx, d));
        float s = __expf(v0 - mx) + __expf(v1 - mx) + (valid2 ? __expf(v2 - mx) : 0.0f);
#pragma unroll
        for (int d = 1; d < 16; d <<= 1) s += __shfl_xor(s, d);
        float lg = mx + __logf(s);
        size_t o0 = (size_t)row * C_OUT + l15;
        if (f32out) {
            of[o0]      = v0 - lg;
            of[o0 + 16] = v1 - lg;
            if (valid2) of[o0 + 32] = v2 - lg;
        } else {
            ob[o0]      = f2bf(v0 - lg);
            ob[o0 + 16] = f2bf(v1 - lg);
            if (valid2) ob[o0 + 32] = f2bf(v2 - lg);
        }
    }
}

// ---------------------------------------------------------------------------
extern "C" void kernel_launch(void* const* d_in, const int* in_sizes, int n_in,
                              void* d_out, int out_size, void* d_ws, size_t ws_size,
                              hipStream_t stream) {
    const void* x      = d_in[0];
    const int*  ei     = (const int*)d_in[1];
    const void* w_in   = d_in[2];
    const void* w_out  = d_in[3];
    const void* conv_w = d_in[4];
    const void* w_ih   = d_in[5];
    const void* w_hh   = d_in[6];
    const void* b_ih   = d_in[7];
    const void* b_hh   = d_in[8];

    const int E   = in_sizes[1] / 2;
    const int nwg = (E + CH - 1) / CH;   // 147 for E=1.2M (must be <= 256)

    // workspace carve-up (256B aligned). Total ~38.5 MB.
    char* ws = (char*)d_ws;
    size_t off = 0;
    auto carve = [&](size_t bytes) {
        void* p = ws + off;
        off += (bytes + 255) & ~(size_t)255;
        return p;
    };
    int*            flags    = (int*)carve(256);
    unsigned short* aggB     = (unsigned short*)carve((size_t)N_NODES * H_DIM * 2); // 12.8 MB
    unsigned short* hbuf     = (unsigned short*)carve((size_t)N_NODES * H_DIM * 2); // 12.8 MB
    int*            counts   = (int*)carve((size_t)N_NODES * 4);                    // 0.4 MB
    int*            rowptr   = (int*)carve((size_t)N_NODES * 4);                    // 0.4 MB
    int*            wgsorted = (int*)carve((size_t)nwg * CH * 4);                   // 4.8 MB
    int*            lbase_g  = (int*)carve((size_t)nwg * LB_STRIDE * 4);            // 0.46 MB
    int*            esrcP    = (int*)carve((size_t)NBUCK * BCAP * 4);               // 6.4 MB
    unsigned short* winfrag  = (unsigned short*)carve((size_t)8 * 4 * 512 * 2);
    unsigned short* wcomb    = (unsigned short*)carve((size_t)4 * 12288 * 2);
    unsigned short* wofrag   = (unsigned short*)carve((size_t)3072 * 2);
    unsigned short* whh_c    = (unsigned short*)carve((size_t)12288 * 2);
    unsigned short* bias_c   = (unsigned short*)carve((size_t)384 * 2);

    // ---- probe ----
    detect_kernel<<<1, 64, 0, stream>>>(x, ei, flags);

    // ---- CSR build: two-level counting sort (atomic-free, coalesced) ----
    bucket_local<<<nwg, 256, 0, stream>>>(ei, E, flags, wgsorted, lbase_g);
    bucket_csr<<<NBUCK, 256, 0, stream>>>(wgsorted, lbase_g, nwg,
                                          rowptr, counts, esrcP);

    // ---- weight prep ----
    prep_bfrag<<<64, 256, 0, stream>>>(w_in, winfrag, 256, 4, 64, flags);
    prep_bfrag<<<12, 256, 0, stream>>>(w_out, wofrag, 64, 3, 40, flags);
    wcomb_kernel<<<dim3(24, 4), 64, 0, stream>>>(conv_w, w_ih, wcomb, flags);
    prep_gruw<<<50, 256, 0, stream>>>(w_hh, b_ih, b_hh, whh_c, bias_c, flags);

    const int gblocks = (ROW_TILES + 3) / 4;  // 1563
    const int nblocks = N_NODES / 4;          // 25000

    // ---- input projection ----
    proj_in_kernel<<<gblocks, 256, 0, stream>>>(x, winfrag, hbuf, flags);

    // ---- GGNN layers ----
    for (int l = 0; l < 4; ++l) {
        gather_agg<<<nblocks, 256, 0, stream>>>(hbuf, rowptr, counts, esrcP, aggB);
        gru_kernel<<<gblocks, 256, 0, stream>>>(aggB, hbuf, wcomb + (size_t)l * 12288,
                                                whh_c, bias_c);
    }

    // ---- output projection + log_softmax ----
    projout_kernel<<<gblocks, 256, 0, stream>>>(hbuf, wofrag, d_out, flags);
}